// Round 8
// baseline (318.780 us; speedup 1.0000x reference)
//
#include <hip/hip_runtime.h>
#include <hip/hip_bf16.h>

#define NFACE 400000
#define NVERT 200000
#define CIN 64
#define COUT 128
#define KF 27
#define CAP 32            // max faces/vertex (Poisson(6), observed max ~21)
#define BN_EPS 1e-5f
#define LST 56            // Af row stride (shorts): 112B, bank-spread
#define BST 40            // Bs/swb row stride (shorts): 80B, bank-spread

typedef __attribute__((ext_vector_type(8))) short bf16x8;
typedef __attribute__((ext_vector_type(4))) float f32x4;

__device__ __forceinline__ short f2bf(float x) {
    __hip_bfloat16 h = __float2bfloat16(x);
    return *reinterpret_cast<short*>(&h);
}

// ---- prep: sw [27,64] f32 -> swb [64 ch][BST k] bf16 (zero-padded K) -----
__global__ __launch_bounds__(256) void prep_k(const float* __restrict__ sw,
                                              short* __restrict__ swb) {
    int t = threadIdx.x;
#pragma unroll
    for (int j = 0; j < 10; ++j) {          // 64*BST = 2560 cells
        int cell = t + j * 256;
        if (cell < 64 * BST) {
            int ch = cell / BST, k = cell % BST;
            float v = (k < KF) ? sw[k * 64 + ch] : 0.f;
            swb[cell] = f2bf(v);
        }
    }
}

// ---- adjacency build (separate, random atomics isolated) -----------------
__global__ __launch_bounds__(256) void fill_adj_k(
    const int* __restrict__ face, int* __restrict__ counts, int* __restrict__ adj)
{
    int f = blockIdx.x * 256 + threadIdx.x;
    if (f >= NFACE) return;
    int v0 = face[f * 3 + 0];
    int v1 = face[f * 3 + 1];
    int v2 = face[f * 3 + 2];
    int s0 = atomicAdd(&counts[v0], 1);
    if (s0 < CAP) adj[v0 * CAP + s0] = f;
    int s1 = atomicAdd(&counts[v1], 1);
    if (s1 < CAP) adj[v1 * CAP + s1] = f;
    int s2 = atomicAdd(&counts[v2], 1);
    if (s2 < CAP) adj[v2 * CAP + s2] = f;
}

// ---- Kernel: MFMA spatial mix + coalesced elementwise --------------------
// 256 threads = 4 waves; 64 faces per block.
__global__ __launch_bounds__(256) void mix_k(
    const float* __restrict__ inputs,   // [NF,64]
    const float* __restrict__ filt,     // [NF,27]
    const short* __restrict__ swb,      // [64][BST] bf16 (prepped)
    __hip_bfloat16* __restrict__ contrib) // [NF,64]
{
    __shared__ __align__(16) char smem[16384];
    short* Af = (short*)smem;                 // 64*LST*2 = 7168 B
    short* Bs = (short*)(smem + 7168);        // 64*BST*2 = 5120 B
    float (*Wt)[64] = (float (*)[64])smem;    // phase 2 reuse: 16384 B

    const int t  = threadIdx.x;
    const int fb = blockIdx.x * 64;

    // stage B panel: coalesced float4 copies (5120 B = 320 x 16 B)
    for (int i = t; i < 320; i += 256)
        ((float4*)Bs)[i] = ((const float4*)swb)[i];
    // stage filt tile (coalesced 8B per thread per iter)
#pragma unroll
    for (int j = 0; j < 4; ++j) {
        int idx = t + j * 256;                // 64 faces * 16 k-pairs
        int fl = idx >> 4, k = (idx & 15) * 2;
        const float* fr = filt + (size_t)(fb + fl) * KF;
        float v0 = (k     < KF) ? fr[k]     : 0.f;
        float v1 = (k + 1 < KF) ? fr[k + 1] : 0.f;
        Af[fl * LST + k]     = f2bf(v0);
        Af[fl * LST + k + 1] = f2bf(v1);
    }
    __syncthreads();

    const int lane = t & 63;
    const int wid  = t >> 6;
    const int r0   = wid * 16;                // wave's 16 faces

    bf16x8 a = *(const bf16x8*)&Af[(r0 + (lane & 15)) * LST + (lane >> 4) * 8];
    f32x4 acc[4];
#pragma unroll
    for (int cb = 0; cb < 4; ++cb) {
        bf16x8 b = *(const bf16x8*)&Bs[(cb * 16 + (lane & 15)) * BST + (lane >> 4) * 8];
        acc[cb] = __builtin_amdgcn_mfma_f32_16x16x32_bf16(a, b, (f32x4){0.f, 0.f, 0.f, 0.f}, 0, 0, 0);
    }
    __syncthreads();   // all waves done reading Af/Bs before Wt overwrite

    // scatter W fragments to LDS (verified C layout: col=lane&15, row=(lane>>4)*4+i)
#pragma unroll
    for (int cb = 0; cb < 4; ++cb)
#pragma unroll
        for (int i = 0; i < 4; ++i)
            Wt[r0 + (lane >> 4) * 4 + i][cb * 16 + (lane & 15)] = acc[cb][i];
    __syncthreads();

    // fully-coalesced elementwise: float4 in, float4 W, 8B bf16 out
#pragma unroll
    for (int p = 0; p < 4; ++p) {
        int idx = (p * 256 + t) * 4;          // 0..4095 floats
        int fl = idx >> 6, c = idx & 63;
        float4 in4 = *(const float4*)&inputs[(size_t)(fb + fl) * 64 + c];
        float4 w4  = *(const float4*)&Wt[fl][c];
        short4 o;
        o.x = f2bf(in4.x * w4.x);
        o.y = f2bf(in4.y * w4.y);
        o.z = f2bf(in4.z * w4.z);
        o.w = f2bf(in4.w * w4.w);
        *(short4*)((short*)contrib + (size_t)fb * 64 + idx) = o;
    }
}

// ---- per-vertex gather with MLP ------------------------------------------
__global__ __launch_bounds__(256) void gather2_k(
    const __hip_bfloat16* __restrict__ contrib, // [NF,64]
    const int* __restrict__ counts,             // [NV]
    const int* __restrict__ adj,                // [NV,CAP]
    const int* __restrict__ nf_count,           // [NV]
    float* __restrict__ agg)                    // [NV,64] (already /denom)
{
    const int lane = threadIdx.x & 63;
    const int src  = blockIdx.x * 4 + (threadIdx.x >> 6);
    int n = counts[src];
    n = n > CAP ? CAP : n;
    int adjv = (lane < n) ? adj[src * CAP + lane] : 0;

    float acc = 0.f;
    int j = 0;
    for (; j + 4 <= n; j += 4) {
        int f0 = __shfl(adjv, j + 0);
        int f1 = __shfl(adjv, j + 1);
        int f2 = __shfl(adjv, j + 2);
        int f3 = __shfl(adjv, j + 3);
        float a0 = __bfloat162float(contrib[(size_t)f0 * 64 + lane]);
        float a1 = __bfloat162float(contrib[(size_t)f1 * 64 + lane]);
        float a2 = __bfloat162float(contrib[(size_t)f2 * 64 + lane]);
        float a3 = __bfloat162float(contrib[(size_t)f3 * 64 + lane]);
        acc += (a0 + a1) + (a2 + a3);
    }
    for (; j < n; ++j) {
        int f = __shfl(adjv, j);
        acc += __bfloat162float(contrib[(size_t)f * 64 + lane]);
    }
    float denom = (float)max(nf_count[src], 1);
    agg[(size_t)src * 64 + lane] = acc / denom;
}

// ---- pointwise conv + bias + ReLU + BN stats -----------------------------
#define BV 32
__global__ __launch_bounds__(256) void pconv_k(
    const float* __restrict__ agg,       // [NV,64] (pre-divided)
    const int* __restrict__ vt_map,      // [NV] (int32)
    const float* __restrict__ dw,        // [64,128]
    const float* __restrict__ bias,      // [128]
    float* __restrict__ out,             // [NV,128]
    float* __restrict__ stats)           // [8][256]
{
    __shared__ float A[BV][64];
    const int c = threadIdx.x & 127;

    float wreg[64];
#pragma unroll
    for (int k = 0; k < 64; ++k) wreg[k] = dw[k * 128 + c];

    const int vbase = blockIdx.x * BV;
    for (int i = threadIdx.x; i < BV * 64; i += 256) {
        int vv = vbase + (i >> 6);
        int src = vt_map[vv];
        A[i >> 6][i & 63] = agg[(size_t)src * 64 + (i & 63)];
    }
    __syncthreads();

    const int half = threadIdx.x >> 7;
    float s = 0.f, s2 = 0.f;
    for (int vi = half * (BV / 2); vi < (half + 1) * (BV / 2); ++vi) {
        const float4* A4 = reinterpret_cast<const float4*>(&A[vi][0]);
        float acc = bias[c];
#pragma unroll
        for (int k4 = 0; k4 < 16; ++k4) {
            float4 a = A4[k4];
            acc += a.x * wreg[k4 * 4 + 0];
            acc += a.y * wreg[k4 * 4 + 1];
            acc += a.z * wreg[k4 * 4 + 2];
            acc += a.w * wreg[k4 * 4 + 3];
        }
        acc = fmaxf(acc, 0.f);
        out[(size_t)(vbase + vi) * 128 + c] = acc;
        s  += acc;
        s2 += acc * acc;
    }
    float* st = stats + (blockIdx.x & 7) * 256;
    atomicAdd(&st[c], s);
    atomicAdd(&st[128 + c], s2);
}

// ---- BatchNorm finalize (in place on d_out) ------------------------------
__global__ __launch_bounds__(256) void bn_k(
    float* __restrict__ out,
    const float* __restrict__ stats,
    const float* __restrict__ gamma,
    const float* __restrict__ beta)
{
    __shared__ float sc[128], sh[128];
    if (threadIdx.x < 128) {
        int c = threadIdx.x;
        float s = 0.f, s2 = 0.f;
#pragma unroll
        for (int r = 0; r < 8; ++r) {
            s  += stats[r * 256 + c];
            s2 += stats[r * 256 + 128 + c];
        }
        float mean = s / (float)NVERT;
        float var  = s2 / (float)NVERT - mean * mean;
        float inv  = rsqrtf(var + BN_EPS) * gamma[c];
        sc[c] = inv;
        sh[c] = beta[c] - mean * inv;
    }
    __syncthreads();

    float4* o4 = reinterpret_cast<float4*>(out);
    size_t total4 = (size_t)NVERT * COUT / 4;
    for (size_t i = (size_t)blockIdx.x * 256 + threadIdx.x; i < total4;
         i += (size_t)gridDim.x * 256) {
        int c0 = (int)((i * 4) & 127);
        float4 v = o4[i];
        v.x = v.x * sc[c0 + 0] + sh[c0 + 0];
        v.y = v.y * sc[c0 + 1] + sh[c0 + 1];
        v.z = v.z * sc[c0 + 2] + sh[c0 + 2];
        v.w = v.w * sc[c0 + 3] + sh[c0 + 3];
        o4[i] = v;
    }
}

extern "C" void kernel_launch(void* const* d_in, const int* in_sizes, int n_in,
                              void* d_out, int out_size, void* d_ws, size_t ws_size,
                              hipStream_t stream) {
    const float* inputs   = (const float*)d_in[0];
    const float* filt     = (const float*)d_in[1];
    const int*   face     = (const int*)d_in[2];
    const int*   nf_count = (const int*)d_in[3];
    const int*   vt_map   = (const int*)d_in[4];
    const float* sw       = (const float*)d_in[5];
    const float* dw       = (const float*)d_in[6];
    const float* bias     = (const float*)d_in[7];
    const float* gamma    = (const float*)d_in[8];
    const float* beta     = (const float*)d_in[9];
    float* out = (float*)d_out;

    // ws: [stats 8KB][swb 8KB][agg 51.2MB]
    float* stats = (float*)d_ws;
    short* swb   = (short*)((char*)d_ws + 8192);
    float* agg   = (float*)((char*)d_ws + 16384);

    // staged inside d_out (dead before pconv_k overwrites it):
    //   [contrib bf16 51.2MB][adj 25.6MB][counts 0.8MB] = 77.6MB < 102.4MB
    __hip_bfloat16* contrib = (__hip_bfloat16*)d_out;
    int* adj    = (int*)((char*)d_out + (size_t)NFACE * CIN * 2);
    int* counts = (int*)((char*)adj + (size_t)NVERT * CAP * 4);

    hipMemsetAsync(stats, 0, 8192, stream);
    hipMemsetAsync(counts, 0, (size_t)NVERT * sizeof(int), stream);

    prep_k<<<1, 256, 0, stream>>>(sw, swb);
    fill_adj_k<<<(NFACE + 255) / 256, 256, 0, stream>>>(face, counts, adj);
    mix_k<<<NFACE / 64, 256, 0, stream>>>(inputs, filt, swb, contrib);
    gather2_k<<<NVERT / 4, 256, 0, stream>>>(contrib, counts, adj, nf_count, agg);
    pconv_k<<<NVERT / BV, 256, 0, stream>>>(agg, vt_map, dw, bias, out, stats);
    bn_k<<<2048, 256, 0, stream>>>(out, stats, gamma, beta);
}

// Round 9
// 277.451 us; speedup vs baseline: 1.1490x; 1.1490x over previous
//
#include <hip/hip_runtime.h>
#include <hip/hip_bf16.h>

#define NFACE 400000
#define NVERT 200000
#define CIN 64
#define COUT 128
#define KF 27
#define CAP 32            // max faces/vertex (Poisson(6), observed max ~21)
#define BN_EPS 1e-5f
#define LST 56            // Af row stride (shorts): 112B, bank-spread
#define BST 40            // Bs/swb row stride (shorts): 80B, bank-spread

typedef __attribute__((ext_vector_type(8))) short bf16x8;
typedef __attribute__((ext_vector_type(4))) float f32x4;

__device__ __forceinline__ short f2bf(float x) {
    __hip_bfloat16 h = __float2bfloat16(x);
    return *reinterpret_cast<short*>(&h);
}

// ---- prep: sw [27,64] f32 -> swb [64 ch][BST k] bf16 (zero-padded K) -----
__global__ __launch_bounds__(256) void prep_k(const float* __restrict__ sw,
                                              short* __restrict__ swb) {
    int t = threadIdx.x;
#pragma unroll
    for (int j = 0; j < 10; ++j) {          // 64*BST = 2560 cells
        int cell = t + j * 256;
        if (cell < 64 * BST) {
            int ch = cell / BST, k = cell % BST;
            float v = (k < KF) ? sw[k * 64 + ch] : 0.f;
            swb[cell] = f2bf(v);
        }
    }
}

// ---- Kernel: MFMA spatial mix + coalesced elementwise + adjacency --------
// 256 threads = 4 waves; 64 faces per block. Adjacency atomics fused here:
// they have no dependent reads, so their random-write traffic hides under
// the streaming phases of this kernel instead of costing a serial 97us.
__global__ __launch_bounds__(256) void mix_k(
    const float* __restrict__ inputs,   // [NF,64]
    const float* __restrict__ filt,     // [NF,27]
    const int*   __restrict__ face,     // [NF,3]
    const short* __restrict__ swb,      // [64][BST] bf16 (prepped)
    __hip_bfloat16* __restrict__ contrib, // [NF,64]
    int* __restrict__ counts,           // [NV]
    int* __restrict__ adj)              // [NV,CAP]
{
    __shared__ __align__(16) char smem[16384];
    short* Af = (short*)smem;                 // 64*LST*2 = 7168 B
    short* Bs = (short*)(smem + 7168);        // 64*BST*2 = 5120 B
    float (*Wt)[64] = (float (*)[64])smem;    // phase 2 reuse: 16384 B

    const int t  = threadIdx.x;
    const int fb = blockIdx.x * 64;

    // adjacency: one (face,corner) per thread for t<192; fire-and-forget
    if (t < 192) {
        int fl = t / 3, vi = t - fl * 3;
        int v = face[(size_t)(fb + fl) * 3 + vi];
        int s = atomicAdd(&counts[v], 1);
        if (s < CAP) adj[v * CAP + s] = fb + fl;
    }

    // stage B panel: coalesced float4 copies (5120 B = 320 x 16 B)
    for (int i = t; i < 320; i += 256)
        ((float4*)Bs)[i] = ((const float4*)swb)[i];
    // stage filt tile (coalesced 8B per thread per iter)
#pragma unroll
    for (int j = 0; j < 4; ++j) {
        int idx = t + j * 256;                // 64 faces * 16 k-pairs
        int fl = idx >> 4, k = (idx & 15) * 2;
        const float* fr = filt + (size_t)(fb + fl) * KF;
        float v0 = (k     < KF) ? fr[k]     : 0.f;
        float v1 = (k + 1 < KF) ? fr[k + 1] : 0.f;
        Af[fl * LST + k]     = f2bf(v0);
        Af[fl * LST + k + 1] = f2bf(v1);
    }
    __syncthreads();

    const int lane = t & 63;
    const int wid  = t >> 6;
    const int r0   = wid * 16;                // wave's 16 faces

    bf16x8 a = *(const bf16x8*)&Af[(r0 + (lane & 15)) * LST + (lane >> 4) * 8];
    f32x4 acc[4];
#pragma unroll
    for (int cb = 0; cb < 4; ++cb) {
        bf16x8 b = *(const bf16x8*)&Bs[(cb * 16 + (lane & 15)) * BST + (lane >> 4) * 8];
        acc[cb] = __builtin_amdgcn_mfma_f32_16x16x32_bf16(a, b, (f32x4){0.f, 0.f, 0.f, 0.f}, 0, 0, 0);
    }
    __syncthreads();   // all waves done reading Af/Bs before Wt overwrite

    // scatter W fragments to LDS (verified C layout: col=lane&15, row=(lane>>4)*4+i)
#pragma unroll
    for (int cb = 0; cb < 4; ++cb)
#pragma unroll
        for (int i = 0; i < 4; ++i)
            Wt[r0 + (lane >> 4) * 4 + i][cb * 16 + (lane & 15)] = acc[cb][i];
    __syncthreads();

    // fully-coalesced elementwise: float4 in, float4 W, 8B bf16 out
#pragma unroll
    for (int p = 0; p < 4; ++p) {
        int idx = (p * 256 + t) * 4;          // 0..4095 floats
        int fl = idx >> 6, c = idx & 63;
        float4 in4 = *(const float4*)&inputs[(size_t)(fb + fl) * 64 + c];
        float4 w4  = *(const float4*)&Wt[fl][c];
        short4 o;
        o.x = f2bf(in4.x * w4.x);
        o.y = f2bf(in4.y * w4.y);
        o.z = f2bf(in4.z * w4.z);
        o.w = f2bf(in4.w * w4.w);
        *(short4*)((short*)contrib + (size_t)fb * 64 + idx) = o;
    }
}

// ---- per-vertex gather with MLP ------------------------------------------
__global__ __launch_bounds__(256) void gather2_k(
    const __hip_bfloat16* __restrict__ contrib, // [NF,64]
    const int* __restrict__ counts,             // [NV]
    const int* __restrict__ adj,                // [NV,CAP]
    const int* __restrict__ nf_count,           // [NV]
    float* __restrict__ agg)                    // [NV,64] (already /denom)
{
    const int lane = threadIdx.x & 63;
    const int src  = blockIdx.x * 4 + (threadIdx.x >> 6);
    int n = counts[src];
    n = n > CAP ? CAP : n;
    int adjv = (lane < n) ? adj[src * CAP + lane] : 0;

    float acc = 0.f;
    int j = 0;
    for (; j + 4 <= n; j += 4) {
        int f0 = __shfl(adjv, j + 0);
        int f1 = __shfl(adjv, j + 1);
        int f2 = __shfl(adjv, j + 2);
        int f3 = __shfl(adjv, j + 3);
        float a0 = __bfloat162float(contrib[(size_t)f0 * 64 + lane]);
        float a1 = __bfloat162float(contrib[(size_t)f1 * 64 + lane]);
        float a2 = __bfloat162float(contrib[(size_t)f2 * 64 + lane]);
        float a3 = __bfloat162float(contrib[(size_t)f3 * 64 + lane]);
        acc += (a0 + a1) + (a2 + a3);
    }
    for (; j < n; ++j) {
        int f = __shfl(adjv, j);
        acc += __bfloat162float(contrib[(size_t)f * 64 + lane]);
    }
    float denom = (float)max(nf_count[src], 1);
    agg[(size_t)src * 64 + lane] = acc / denom;
}

// ---- pointwise conv + bias + ReLU + BN stats -----------------------------
#define BV 32
__global__ __launch_bounds__(256) void pconv_k(
    const float* __restrict__ agg,       // [NV,64] (pre-divided)
    const int* __restrict__ vt_map,      // [NV] (int32)
    const float* __restrict__ dw,        // [64,128]
    const float* __restrict__ bias,      // [128]
    float* __restrict__ out,             // [NV,128]
    float* __restrict__ stats)           // [8][256]
{
    __shared__ float A[BV][64];
    const int c = threadIdx.x & 127;

    float wreg[64];
#pragma unroll
    for (int k = 0; k < 64; ++k) wreg[k] = dw[k * 128 + c];

    const int vbase = blockIdx.x * BV;
    for (int i = threadIdx.x; i < BV * 64; i += 256) {
        int vv = vbase + (i >> 6);
        int src = vt_map[vv];
        A[i >> 6][i & 63] = agg[(size_t)src * 64 + (i & 63)];
    }
    __syncthreads();

    const int half = threadIdx.x >> 7;
    float s = 0.f, s2 = 0.f;
    for (int vi = half * (BV / 2); vi < (half + 1) * (BV / 2); ++vi) {
        const float4* A4 = reinterpret_cast<const float4*>(&A[vi][0]);
        float acc = bias[c];
#pragma unroll
        for (int k4 = 0; k4 < 16; ++k4) {
            float4 a = A4[k4];
            acc += a.x * wreg[k4 * 4 + 0];
            acc += a.y * wreg[k4 * 4 + 1];
            acc += a.z * wreg[k4 * 4 + 2];
            acc += a.w * wreg[k4 * 4 + 3];
        }
        acc = fmaxf(acc, 0.f);
        out[(size_t)(vbase + vi) * 128 + c] = acc;
        s  += acc;
        s2 += acc * acc;
    }
    float* st = stats + (blockIdx.x & 7) * 256;
    atomicAdd(&st[c], s);
    atomicAdd(&st[128 + c], s2);
}

// ---- BatchNorm finalize (in place on d_out) ------------------------------
__global__ __launch_bounds__(256) void bn_k(
    float* __restrict__ out,
    const float* __restrict__ stats,
    const float* __restrict__ gamma,
    const float* __restrict__ beta)
{
    __shared__ float sc[128], sh[128];
    if (threadIdx.x < 128) {
        int c = threadIdx.x;
        float s = 0.f, s2 = 0.f;
#pragma unroll
        for (int r = 0; r < 8; ++r) {
            s  += stats[r * 256 + c];
            s2 += stats[r * 256 + 128 + c];
        }
        float mean = s / (float)NVERT;
        float var  = s2 / (float)NVERT - mean * mean;
        float inv  = rsqrtf(var + BN_EPS) * gamma[c];
        sc[c] = inv;
        sh[c] = beta[c] - mean * inv;
    }
    __syncthreads();

    float4* o4 = reinterpret_cast<float4*>(out);
    size_t total4 = (size_t)NVERT * COUT / 4;
    for (size_t i = (size_t)blockIdx.x * 256 + threadIdx.x; i < total4;
         i += (size_t)gridDim.x * 256) {
        int c0 = (int)((i * 4) & 127);
        float4 v = o4[i];
        v.x = v.x * sc[c0 + 0] + sh[c0 + 0];
        v.y = v.y * sc[c0 + 1] + sh[c0 + 1];
        v.z = v.z * sc[c0 + 2] + sh[c0 + 2];
        v.w = v.w * sc[c0 + 3] + sh[c0 + 3];
        o4[i] = v;
    }
}

extern "C" void kernel_launch(void* const* d_in, const int* in_sizes, int n_in,
                              void* d_out, int out_size, void* d_ws, size_t ws_size,
                              hipStream_t stream) {
    const float* inputs   = (const float*)d_in[0];
    const float* filt     = (const float*)d_in[1];
    const int*   face     = (const int*)d_in[2];
    const int*   nf_count = (const int*)d_in[3];
    const int*   vt_map   = (const int*)d_in[4];
    const float* sw       = (const float*)d_in[5];
    const float* dw       = (const float*)d_in[6];
    const float* bias     = (const float*)d_in[7];
    const float* gamma    = (const float*)d_in[8];
    const float* beta     = (const float*)d_in[9];
    float* out = (float*)d_out;

    // ws: [stats 8KB][swb 8KB][agg 51.2MB]
    float* stats = (float*)d_ws;
    short* swb   = (short*)((char*)d_ws + 8192);
    float* agg   = (float*)((char*)d_ws + 16384);

    // staged inside d_out (dead before pconv_k overwrites it):
    //   [contrib bf16 51.2MB][adj 25.6MB][counts 0.8MB] = 77.6MB < 102.4MB
    __hip_bfloat16* contrib = (__hip_bfloat16*)d_out;
    int* adj    = (int*)((char*)d_out + (size_t)NFACE * CIN * 2);
    int* counts = (int*)((char*)adj + (size_t)NVERT * CAP * 4);

    hipMemsetAsync(stats, 0, 8192, stream);
    hipMemsetAsync(counts, 0, (size_t)NVERT * sizeof(int), stream);

    prep_k<<<1, 256, 0, stream>>>(sw, swb);
    mix_k<<<NFACE / 64, 256, 0, stream>>>(inputs, filt, face, swb,
                                          contrib, counts, adj);
    gather2_k<<<NVERT / 4, 256, 0, stream>>>(contrib, counts, adj, nf_count, agg);
    pconv_k<<<NVERT / BV, 256, 0, stream>>>(agg, vt_map, dw, bias, out, stats);
    bn_k<<<2048, 256, 0, stream>>>(out, stats, gamma, beta);
}

// Round 10
// 276.857 us; speedup vs baseline: 1.1514x; 1.0021x over previous
//
#include <hip/hip_runtime.h>
#include <hip/hip_bf16.h>

#define NFACE 400000
#define NVERT 200000
#define CIN 64
#define COUT 128
#define KF 27
#define BN_EPS 1e-5f
#define LST 56            // Af row stride (shorts): 112B, bank-spread
#define BST 40            // Bs/swb row stride (shorts): 80B, bank-spread

typedef __attribute__((ext_vector_type(8))) short bf16x8;
typedef __attribute__((ext_vector_type(4))) float f32x4;

__device__ __forceinline__ short f2bf(float x) {
    __hip_bfloat16 h = __float2bfloat16(x);
    return *reinterpret_cast<short*>(&h);
}
__device__ __forceinline__ float bf2f(unsigned short u) {
    union { unsigned int i; float f; } x; x.i = ((unsigned)u) << 16; return x.f;
}

// ---- prep: sw [27,64] f32 -> swb [64 ch][BST k] bf16 (zero-padded K) -----
__global__ __launch_bounds__(256) void prep_k(const float* __restrict__ sw,
                                              short* __restrict__ swb) {
    int t = threadIdx.x;
#pragma unroll
    for (int j = 0; j < 10; ++j) {          // 64*BST = 2560 cells
        int cell = t + j * 256;
        if (cell < 64 * BST) {
            int ch = cell / BST, k = cell % BST;
            float v = (k < KF) ? sw[k * 64 + ch] : 0.f;
            swb[cell] = f2bf(v);
        }
    }
}

// ---- Kernel: MFMA spatial mix + coalesced elementwise + packed adjacency -
// adj row (64B line): [count | f0..f14]; overflow rows in adj2 (deg<=31).
// Atomic and its dependent slot-store hit the SAME line -> ~200K dirty lines
// instead of ~1.1M.
__global__ __launch_bounds__(256) void mix_k(
    const float* __restrict__ inputs,   // [NF,64]
    const float* __restrict__ filt,     // [NF,27]
    const int*   __restrict__ face,     // [NF,3]
    const short* __restrict__ swb,      // [64][BST] bf16 (prepped)
    __hip_bfloat16* __restrict__ contrib, // [NF,64]
    int* __restrict__ adj,              // [NV,16] packed
    int* __restrict__ adj2)             // [NV,16] overflow
{
    __shared__ __align__(16) char smem[16384];
    short* Af = (short*)smem;                 // 64*LST*2 = 7168 B
    short* Bs = (short*)(smem + 7168);        // 64*BST*2 = 5120 B
    float (*Wt)[64] = (float (*)[64])smem;    // phase 2 reuse: 16384 B

    const int t  = threadIdx.x;
    const int fb = blockIdx.x * 64;

    // adjacency: one (face,corner) per thread for t<192; fire-and-forget
    if (t < 192) {
        int fl = t / 3, vi = t - fl * 3;
        int v = face[(size_t)(fb + fl) * 3 + vi];
        int s = atomicAdd(&adj[(size_t)v * 16], 1);
        if (s < 15)       adj[(size_t)v * 16 + 1 + s] = fb + fl;   // same line
        else if (s < 31)  adj2[(size_t)v * 16 + (s - 15)] = fb + fl;
    }

    // stage B panel: coalesced float4 copies (5120 B = 320 x 16 B)
    for (int i = t; i < 320; i += 256)
        ((float4*)Bs)[i] = ((const float4*)swb)[i];
    // stage filt tile (coalesced 8B per thread per iter)
#pragma unroll
    for (int j = 0; j < 4; ++j) {
        int idx = t + j * 256;                // 64 faces * 16 k-pairs
        int fl = idx >> 4, k = (idx & 15) * 2;
        const float* fr = filt + (size_t)(fb + fl) * KF;
        float v0 = (k     < KF) ? fr[k]     : 0.f;
        float v1 = (k + 1 < KF) ? fr[k + 1] : 0.f;
        Af[fl * LST + k]     = f2bf(v0);
        Af[fl * LST + k + 1] = f2bf(v1);
    }
    __syncthreads();

    const int lane = t & 63;
    const int wid  = t >> 6;
    const int r0   = wid * 16;                // wave's 16 faces

    bf16x8 a = *(const bf16x8*)&Af[(r0 + (lane & 15)) * LST + (lane >> 4) * 8];
    f32x4 acc[4];
#pragma unroll
    for (int cb = 0; cb < 4; ++cb) {
        bf16x8 b = *(const bf16x8*)&Bs[(cb * 16 + (lane & 15)) * BST + (lane >> 4) * 8];
        acc[cb] = __builtin_amdgcn_mfma_f32_16x16x32_bf16(a, b, (f32x4){0.f, 0.f, 0.f, 0.f}, 0, 0, 0);
    }
    __syncthreads();   // all waves done reading Af/Bs before Wt overwrite

    // scatter W fragments to LDS (C layout: col=lane&15, row=(lane>>4)*4+i)
#pragma unroll
    for (int cb = 0; cb < 4; ++cb)
#pragma unroll
        for (int i = 0; i < 4; ++i)
            Wt[r0 + (lane >> 4) * 4 + i][cb * 16 + (lane & 15)] = acc[cb][i];
    __syncthreads();

    // fully-coalesced elementwise: float4 in, float4 W, 8B bf16 out
#pragma unroll
    for (int p = 0; p < 4; ++p) {
        int idx = (p * 256 + t) * 4;          // 0..4095 floats
        int fl = idx >> 6, c = idx & 63;
        float4 in4 = *(const float4*)&inputs[(size_t)(fb + fl) * 64 + c];
        float4 w4  = *(const float4*)&Wt[fl][c];
        short4 o;
        o.x = f2bf(in4.x * w4.x);
        o.y = f2bf(in4.y * w4.y);
        o.z = f2bf(in4.z * w4.z);
        o.w = f2bf(in4.w * w4.w);
        *(short4*)((short*)contrib + (size_t)fb * 64 + idx) = o;
    }
}

// ---- pconv: fused gather + pointwise conv + bias + ReLU + BN stats -------
// Writes ONLY to ws (bf16 out) + stats -> no race with d_out staging.
#define BV 32
__global__ __launch_bounds__(256) void pconv_k(
    const __hip_bfloat16* __restrict__ contrib, // [NF,64]
    const int* __restrict__ adj,                // [NV,16] packed
    const int* __restrict__ adj2,               // [NV,16] overflow
    const int* __restrict__ nf_count,           // [NV]
    const int* __restrict__ vt_map,             // [NV] (int32)
    const float* __restrict__ dw,               // [64,128]
    const float* __restrict__ bias,             // [128]
    __hip_bfloat16* __restrict__ outb,          // [NV,128] bf16 (ws)
    float* __restrict__ stats)                  // [8][256]
{
    __shared__ float A[BV][64];
    const int t    = threadIdx.x;
    const int lane = t & 63;
    const int wid  = t >> 6;
    const int c    = t & 127;
    const int vbase = blockIdx.x * BV;

    // weight column in registers (overlaps with gather latency)
    float wreg[64];
#pragma unroll
    for (int k = 0; k < 64; ++k) wreg[k] = dw[k * 128 + c];

    // gather phase: each wave produces 8 A-rows
    for (int q = 0; q < 8; ++q) {
        int vv  = vbase + wid * 8 + q;
        int src = vt_map[vv];
        int av  = (lane < 16) ? adj[(size_t)src * 16 + lane] : 0;
        int n   = __shfl(av, 0);
        n = n > 31 ? 31 : n;
        int nmain = n > 15 ? 15 : n;

        float acc = 0.f;
        int j = 0;
        for (; j + 4 <= nmain; j += 4) {
            int f0 = __shfl(av, 1 + j);
            int f1 = __shfl(av, 2 + j);
            int f2 = __shfl(av, 3 + j);
            int f3 = __shfl(av, 4 + j);
            float a0 = __bfloat162float(contrib[(size_t)f0 * 64 + lane]);
            float a1 = __bfloat162float(contrib[(size_t)f1 * 64 + lane]);
            float a2 = __bfloat162float(contrib[(size_t)f2 * 64 + lane]);
            float a3 = __bfloat162float(contrib[(size_t)f3 * 64 + lane]);
            acc += (a0 + a1) + (a2 + a3);
        }
        for (; j < nmain; ++j) {
            int f = __shfl(av, 1 + j);
            acc += __bfloat162float(contrib[(size_t)f * 64 + lane]);
        }
        if (n > 15) {
            int av2 = (lane < 16) ? adj2[(size_t)src * 16 + lane] : 0;
            for (int j2 = 0; j2 < n - 15; ++j2) {
                int f = __shfl(av2, j2);
                acc += __bfloat162float(contrib[(size_t)f * 64 + lane]);
            }
        }
        float denom = (float)max(nf_count[src], 1);
        A[wid * 8 + q][lane] = acc / denom;
    }
    __syncthreads();

    // matmul phase
    const int half = t >> 7;
    float s = 0.f, s2 = 0.f;
    for (int vi = half * (BV / 2); vi < (half + 1) * (BV / 2); ++vi) {
        const float4* A4 = reinterpret_cast<const float4*>(&A[vi][0]);
        float acc = bias[c];
#pragma unroll
        for (int k4 = 0; k4 < 16; ++k4) {
            float4 a = A4[k4];
            acc += a.x * wreg[k4 * 4 + 0];
            acc += a.y * wreg[k4 * 4 + 1];
            acc += a.z * wreg[k4 * 4 + 2];
            acc += a.w * wreg[k4 * 4 + 3];
        }
        acc = fmaxf(acc, 0.f);
        outb[(size_t)(vbase + vi) * 128 + c] = __float2bfloat16(acc);
        s  += acc;
        s2 += acc * acc;
    }
    float* st = stats + (blockIdx.x & 7) * 256;
    atomicAdd(&st[c], s);
    atomicAdd(&st[128 + c], s2);
}

// ---- BatchNorm finalize: bf16 in (ws) -> f32 out (d_out) -----------------
__global__ __launch_bounds__(256) void bn_k(
    const __hip_bfloat16* __restrict__ outb,
    float* __restrict__ out,
    const float* __restrict__ stats,
    const float* __restrict__ gamma,
    const float* __restrict__ beta)
{
    __shared__ float sc[128], sh[128];
    if (threadIdx.x < 128) {
        int c = threadIdx.x;
        float s = 0.f, s2 = 0.f;
#pragma unroll
        for (int r = 0; r < 8; ++r) {
            s  += stats[r * 256 + c];
            s2 += stats[r * 256 + 128 + c];
        }
        float mean = s / (float)NVERT;
        float var  = s2 / (float)NVERT - mean * mean;
        float inv  = rsqrtf(var + BN_EPS) * gamma[c];
        sc[c] = inv;
        sh[c] = beta[c] - mean * inv;
    }
    __syncthreads();

    const unsigned short* ob = (const unsigned short*)outb;
    float4* o4 = (float4*)out;
    size_t total4 = (size_t)NVERT * COUT / 4;
    for (size_t i = (size_t)blockIdx.x * 256 + threadIdx.x; i < total4;
         i += (size_t)gridDim.x * 256) {
        int c0 = (int)((i * 4) & 127);
        ushort4 u = *(const ushort4*)&ob[i * 4];
        float4 v;
        v.x = bf2f(u.x) * sc[c0 + 0] + sh[c0 + 0];
        v.y = bf2f(u.y) * sc[c0 + 1] + sh[c0 + 1];
        v.z = bf2f(u.z) * sc[c0 + 2] + sh[c0 + 2];
        v.w = bf2f(u.w) * sc[c0 + 3] + sh[c0 + 3];
        o4[i] = v;
    }
}

extern "C" void kernel_launch(void* const* d_in, const int* in_sizes, int n_in,
                              void* d_out, int out_size, void* d_ws, size_t ws_size,
                              hipStream_t stream) {
    const float* inputs   = (const float*)d_in[0];
    const float* filt     = (const float*)d_in[1];
    const int*   face     = (const int*)d_in[2];
    const int*   nf_count = (const int*)d_in[3];
    const int*   vt_map   = (const int*)d_in[4];
    const float* sw       = (const float*)d_in[5];
    const float* dw       = (const float*)d_in[6];
    const float* bias     = (const float*)d_in[7];
    const float* gamma    = (const float*)d_in[8];
    const float* beta     = (const float*)d_in[9];
    float* out = (float*)d_out;

    // ws: [stats 8KB][swb 8KB][outb bf16 51.2MB]  (same proven footprint)
    float*          stats = (float*)d_ws;
    short*          swb   = (short*)((char*)d_ws + 8192);
    __hip_bfloat16* outb  = (__hip_bfloat16*)((char*)d_ws + 16384);

    // staged inside d_out (read-only for pconv; dead before bn_k writes):
    //   [contrib bf16 51.2MB][adj 12.8MB][adj2 12.8MB] = 76.8MB < 102.4MB
    __hip_bfloat16* contrib = (__hip_bfloat16*)d_out;
    int* adj  = (int*)((char*)d_out + (size_t)NFACE * CIN * 2);
    int* adj2 = (int*)((char*)adj + (size_t)NVERT * 16 * 4);

    hipMemsetAsync(stats, 0, 8192, stream);
    hipMemsetAsync(adj, 0, (size_t)NVERT * 16 * sizeof(int), stream);

    prep_k<<<1, 256, 0, stream>>>(sw, swb);
    mix_k<<<NFACE / 64, 256, 0, stream>>>(inputs, filt, face, swb,
                                          contrib, adj, adj2);
    pconv_k<<<NVERT / BV, 256, 0, stream>>>(contrib, adj, adj2, nf_count,
                                            vt_map, dw, bias, outb, stats);
    bn_k<<<2048, 256, 0, stream>>>(outb, out, stats, gamma, beta);
}

// Round 11
// 232.323 us; speedup vs baseline: 1.3721x; 1.1917x over previous
//
#include <hip/hip_runtime.h>
#include <hip/hip_bf16.h>

#define NFACE 400000
#define NVERT 200000
#define CIN 64
#define COUT 128
#define KF 27
#define BN_EPS 1e-5f
#define LST 56            // Af row stride (shorts): 112B, bank-spread
#define BST 40            // Bs/swb row stride (shorts): 80B, bank-spread

typedef __attribute__((ext_vector_type(8))) short bf16x8;
typedef __attribute__((ext_vector_type(4))) float f32x4;

__device__ __forceinline__ short f2bf(float x) {
    __hip_bfloat16 h = __float2bfloat16(x);
    return *reinterpret_cast<short*>(&h);
}
__device__ __forceinline__ float bf2f(unsigned short u) {
    union { unsigned int i; float f; } x; x.i = ((unsigned)u) << 16; return x.f;
}

// ---- prep: swb (mix B-panel) + dwb (pconv B-fragments), both bf16 --------
// dwb frag order: frag = (nb*4 + t)*2 + kk ; frag[lane][j] =
//   dw[kk*32 + (lane>>4)*8 + j][nb*64 + t*16 + (lane&15)]
__global__ __launch_bounds__(256) void prep_k(const float* __restrict__ sw,
                                              const float* __restrict__ dw,
                                              short* __restrict__ swb,
                                              short* __restrict__ dwb) {
    int t = threadIdx.x;
#pragma unroll
    for (int j = 0; j < 10; ++j) {          // 64*BST = 2560 cells
        int cell = t + j * 256;
        if (cell < 64 * BST) {
            int ch = cell / BST, k = cell % BST;
            float v = (k < KF) ? sw[k * 64 + ch] : 0.f;
            swb[cell] = f2bf(v);
        }
    }
#pragma unroll
    for (int p4 = 0; p4 < 4; ++p4) {        // 1024 (frag,lane) pairs
        int p = t + p4 * 256;
        int frag = p >> 6, lane = p & 63;
        int nb = frag >> 3, tt = (frag >> 1) & 3, kk = frag & 1;
        int col = nb * 64 + tt * 16 + (lane & 15);
#pragma unroll
        for (int j = 0; j < 8; ++j) {
            int k = kk * 32 + (lane >> 4) * 8 + j;
            dwb[(size_t)p * 8 + j] = f2bf(dw[k * 128 + col]);
        }
    }
}

// ---- Kernel: MFMA spatial mix + coalesced elementwise + packed adjacency -
__global__ __launch_bounds__(256) void mix_k(
    const float* __restrict__ inputs,   // [NF,64]
    const float* __restrict__ filt,     // [NF,27]
    const int*   __restrict__ face,     // [NF,3]
    const short* __restrict__ swb,      // [64][BST] bf16 (prepped)
    __hip_bfloat16* __restrict__ contrib, // [NF,64]
    int* __restrict__ adj,              // [NV,16] packed [count|f0..f14]
    int* __restrict__ adj2)             // [NV,16] overflow
{
    __shared__ __align__(16) char smem[16384];
    short* Af = (short*)smem;                 // 64*LST*2 = 7168 B
    short* Bs = (short*)(smem + 7168);        // 64*BST*2 = 5120 B
    float (*Wt)[64] = (float (*)[64])smem;    // phase 2 reuse: 16384 B

    const int t  = threadIdx.x;
    const int fb = blockIdx.x * 64;

    if (t < 192) {
        int fl = t / 3, vi = t - fl * 3;
        int v = face[(size_t)(fb + fl) * 3 + vi];
        int s = atomicAdd(&adj[(size_t)v * 16], 1);
        if (s < 15)       adj[(size_t)v * 16 + 1 + s] = fb + fl;   // same line
        else if (s < 31)  adj2[(size_t)v * 16 + (s - 15)] = fb + fl;
    }

    for (int i = t; i < 320; i += 256)
        ((float4*)Bs)[i] = ((const float4*)swb)[i];
#pragma unroll
    for (int j = 0; j < 4; ++j) {
        int idx = t + j * 256;                // 64 faces * 16 k-pairs
        int fl = idx >> 4, k = (idx & 15) * 2;
        const float* fr = filt + (size_t)(fb + fl) * KF;
        float v0 = (k     < KF) ? fr[k]     : 0.f;
        float v1 = (k + 1 < KF) ? fr[k + 1] : 0.f;
        Af[fl * LST + k]     = f2bf(v0);
        Af[fl * LST + k + 1] = f2bf(v1);
    }
    __syncthreads();

    const int lane = t & 63;
    const int wid  = t >> 6;
    const int r0   = wid * 16;

    bf16x8 a = *(const bf16x8*)&Af[(r0 + (lane & 15)) * LST + (lane >> 4) * 8];
    f32x4 acc[4];
#pragma unroll
    for (int cb = 0; cb < 4; ++cb) {
        bf16x8 b = *(const bf16x8*)&Bs[(cb * 16 + (lane & 15)) * BST + (lane >> 4) * 8];
        acc[cb] = __builtin_amdgcn_mfma_f32_16x16x32_bf16(a, b, (f32x4){0.f, 0.f, 0.f, 0.f}, 0, 0, 0);
    }
    __syncthreads();

#pragma unroll
    for (int cb = 0; cb < 4; ++cb)
#pragma unroll
        for (int i = 0; i < 4; ++i)
            Wt[r0 + (lane >> 4) * 4 + i][cb * 16 + (lane & 15)] = acc[cb][i];
    __syncthreads();

#pragma unroll
    for (int p = 0; p < 4; ++p) {
        int idx = (p * 256 + t) * 4;
        int fl = idx >> 6, c = idx & 63;
        float4 in4 = *(const float4*)&inputs[(size_t)(fb + fl) * 64 + c];
        float4 w4  = *(const float4*)&Wt[fl][c];
        short4 o;
        o.x = f2bf(in4.x * w4.x);
        o.y = f2bf(in4.y * w4.y);
        o.z = f2bf(in4.z * w4.z);
        o.w = f2bf(in4.w * w4.w);
        *(short4*)((short*)contrib + (size_t)fb * 64 + idx) = o;
    }
}

// ---- pconv: gather + MFMA pointwise conv + bias + ReLU + BN stats --------
// Block: 32 vertices, 4 waves. A-tile bf16 in LDS with 16B-chunk XOR swizzle.
#define BV 32
__global__ __launch_bounds__(256) void pconv_k(
    const __hip_bfloat16* __restrict__ contrib, // [NF,64]
    const int* __restrict__ adj,                // [NV,16] packed
    const int* __restrict__ adj2,               // [NV,16] overflow
    const int* __restrict__ nf_count,           // [NV]
    const int* __restrict__ vt_map,             // [NV] (int32)
    const short* __restrict__ dwb,              // prepped dw fragments
    const float* __restrict__ bias,             // [128]
    __hip_bfloat16* __restrict__ outb,          // [NV,128] bf16 (ws)
    float* __restrict__ stats)                  // [8][256]
{
    __shared__ int   srcL[BV];
    __shared__ float denL[BV];
    __shared__ int   adjL[BV][16];
    __shared__ __align__(16) short A[BV * 64];     // swizzled bf16 A-tile, 4KB
    __shared__ __align__(16) short outL[BV * 128]; // C-tile bf16, 8KB

    const int t     = threadIdx.x;
    const int lane  = t & 63;
    const int wid   = t >> 6;
    const int vbase = blockIdx.x * BV;

    if (t < BV) {
        int src = vt_map[vbase + t];
        srcL[t] = src;
        denL[t] = 1.f / (float)max(nf_count[src], 1);
    }
    __syncthreads();
    // stage adjacency rows: 512 ints, 2 per thread, coalesced within rows
#pragma unroll
    for (int r = 0; r < 2; ++r) {
        int i = t + r * 256;
        int row = i >> 4, j = i & 15;
        adjL[row][j] = adj[(size_t)srcL[row] * 16 + j];
    }
    __syncthreads();

    // ---- gather: wave wid produces rows [wid*8, wid*8+8); lane = k-channel
    for (int q0 = 0; q0 < 8; ++q0) {
        int q = wid * 8 + q0;
        int n = adjL[q][0];
        n = n > 31 ? 31 : n;
        int nm = n > 15 ? 15 : n;
        float acc = 0.f;
        int j = 0;
        for (; j + 4 <= nm; j += 4) {
            int f0 = adjL[q][1 + j + 0];
            int f1 = adjL[q][1 + j + 1];
            int f2 = adjL[q][1 + j + 2];
            int f3 = adjL[q][1 + j + 3];
            float a0 = __bfloat162float(contrib[(size_t)f0 * 64 + lane]);
            float a1 = __bfloat162float(contrib[(size_t)f1 * 64 + lane]);
            float a2 = __bfloat162float(contrib[(size_t)f2 * 64 + lane]);
            float a3 = __bfloat162float(contrib[(size_t)f3 * 64 + lane]);
            acc += (a0 + a1) + (a2 + a3);
        }
        for (; j < nm; ++j) {
            int f = adjL[q][1 + j];
            acc += __bfloat162float(contrib[(size_t)f * 64 + lane]);
        }
        if (n > 15) {
            for (int j2 = 0; j2 < n - 15; ++j2) {
                int f = adj2[(size_t)srcL[q] * 16 + j2];
                acc += __bfloat162float(contrib[(size_t)f * 64 + lane]);
            }
        }
        acc *= denL[q];
        // swizzled store: chunk (lane>>3) XOR'd with row&7
        int swz = (lane & 7) | ((((lane >> 3) ^ (q & 7))) << 3);
        A[q * 64 + swz] = f2bf(acc);
    }
    __syncthreads();

    // ---- MFMA matmul: wave (mi, nb): mi = wid&1 (16 rows), nb = wid>>1 (64 cols)
    const int mi = wid & 1;
    const int nb = wid >> 1;
    f32x4 acc[4];
#pragma unroll
    for (int tt = 0; tt < 4; ++tt) acc[tt] = (f32x4){0.f, 0.f, 0.f, 0.f};
#pragma unroll
    for (int kk = 0; kk < 2; ++kk) {
        int row = mi * 16 + (lane & 15);
        int chunk = (kk * 4 + (lane >> 4)) ^ (row & 7);
        bf16x8 a = *(const bf16x8*)&A[row * 64 + chunk * 8];
#pragma unroll
        for (int tt = 0; tt < 4; ++tt) {
            int frag = (nb * 4 + tt) * 2 + kk;
            bf16x8 b = *(const bf16x8*)&dwb[((size_t)frag * 64 + lane) * 8];
            acc[tt] = __builtin_amdgcn_mfma_f32_16x16x32_bf16(a, b, acc[tt], 0, 0, 0);
        }
    }

    // bias + ReLU + C-tile to LDS + BN stats (shfl-reduce over row groups)
    float* st = stats + (blockIdx.x & 7) * 256;
#pragma unroll
    for (int tt = 0; tt < 4; ++tt) {
        int col = nb * 64 + tt * 16 + (lane & 15);
        float bv = bias[col];
        float s = 0.f, s2 = 0.f;
#pragma unroll
        for (int i = 0; i < 4; ++i) {
            float o = fmaxf(acc[tt][i] + bv, 0.f);
            int row = mi * 16 + (lane >> 4) * 4 + i;
            outL[row * 128 + col] = f2bf(o);
            s  += o;
            s2 += o * o;
        }
        s  += __shfl_xor(s, 16);  s  += __shfl_xor(s, 32);
        s2 += __shfl_xor(s2, 16); s2 += __shfl_xor(s2, 32);
        if ((lane >> 4) == 0) {
            atomicAdd(&st[col], s);
            atomicAdd(&st[128 + col], s2);
        }
    }
    __syncthreads();

    // coalesced C write: 4096 shorts = 512 x 16B, 2 per thread
#pragma unroll
    for (int r = 0; r < 2; ++r) {
        int i = t + r * 256;
        ((int4*)&outb[(size_t)vbase * 128])[i] = ((const int4*)outL)[i];
    }
}

// ---- BatchNorm finalize: bf16 in (ws) -> f32 out (d_out) -----------------
__global__ __launch_bounds__(256) void bn_k(
    const __hip_bfloat16* __restrict__ outb,
    float* __restrict__ out,
    const float* __restrict__ stats,
    const float* __restrict__ gamma,
    const float* __restrict__ beta)
{
    __shared__ float sc[128], sh[128];
    if (threadIdx.x < 128) {
        int c = threadIdx.x;
        float s = 0.f, s2 = 0.f;
#pragma unroll
        for (int r = 0; r < 8; ++r) {
            s  += stats[r * 256 + c];
            s2 += stats[r * 256 + 128 + c];
        }
        float mean = s / (float)NVERT;
        float var  = s2 / (float)NVERT - mean * mean;
        float inv  = rsqrtf(var + BN_EPS) * gamma[c];
        sc[c] = inv;
        sh[c] = beta[c] - mean * inv;
    }
    __syncthreads();

    const unsigned short* ob = (const unsigned short*)outb;
    float4* o4 = (float4*)out;
    size_t total4 = (size_t)NVERT * COUT / 4;
    for (size_t i = (size_t)blockIdx.x * 256 + threadIdx.x; i < total4;
         i += (size_t)gridDim.x * 256) {
        int c0 = (int)((i * 4) & 127);
        ushort4 u = *(const ushort4*)&ob[i * 4];
        float4 v;
        v.x = bf2f(u.x) * sc[c0 + 0] + sh[c0 + 0];
        v.y = bf2f(u.y) * sc[c0 + 1] + sh[c0 + 1];
        v.z = bf2f(u.z) * sc[c0 + 2] + sh[c0 + 2];
        v.w = bf2f(u.w) * sc[c0 + 3] + sh[c0 + 3];
        o4[i] = v;
    }
}

extern "C" void kernel_launch(void* const* d_in, const int* in_sizes, int n_in,
                              void* d_out, int out_size, void* d_ws, size_t ws_size,
                              hipStream_t stream) {
    const float* inputs   = (const float*)d_in[0];
    const float* filt     = (const float*)d_in[1];
    const int*   face     = (const int*)d_in[2];
    const int*   nf_count = (const int*)d_in[3];
    const int*   vt_map   = (const int*)d_in[4];
    const float* sw       = (const float*)d_in[5];
    const float* dw       = (const float*)d_in[6];
    const float* bias     = (const float*)d_in[7];
    const float* gamma    = (const float*)d_in[8];
    const float* beta     = (const float*)d_in[9];
    float* out = (float*)d_out;

    // ws: [stats 8KB][swb 8KB][dwb 16KB][outb bf16 51.2MB]
    float*          stats = (float*)d_ws;
    short*          swb   = (short*)((char*)d_ws + 8192);
    short*          dwb   = (short*)((char*)d_ws + 16384);
    __hip_bfloat16* outb  = (__hip_bfloat16*)((char*)d_ws + 32768);

    // staged inside d_out (read-only for pconv; dead before bn_k writes):
    __hip_bfloat16* contrib = (__hip_bfloat16*)d_out;
    int* adj  = (int*)((char*)d_out + (size_t)NFACE * CIN * 2);
    int* adj2 = (int*)((char*)adj + (size_t)NVERT * 16 * 4);

    hipMemsetAsync(stats, 0, 8192, stream);
    hipMemsetAsync(adj, 0, (size_t)NVERT * 16 * sizeof(int), stream);

    prep_k<<<1, 256, 0, stream>>>(sw, dw, swb, dwb);
    mix_k<<<NFACE / 64, 256, 0, stream>>>(inputs, filt, face, swb,
                                          contrib, adj, adj2);
    pconv_k<<<NVERT / BV, 256, 0, stream>>>(contrib, adj, adj2, nf_count,
                                            vt_map, dwb, bias, outb, stats);
    bn_k<<<2048, 256, 0, stream>>>(outb, out, stats, gamma, beta);
}